// Round 17
// baseline (70.047 us; speedup 1.0000x reference)
//
#include <hip/hip_runtime.h>
#include <math.h>

typedef unsigned short u16;
typedef unsigned int   u32;
typedef __attribute__((ext_vector_type(8))) short bf16x8;
typedef __attribute__((ext_vector_type(4))) float f32x4;
typedef __attribute__((ext_vector_type(4))) u32   u32x4;
typedef __attribute__((ext_vector_type(2))) u32   u32x2;

#define NB 8
#define NC 512
#define NS 1024
#define NH 8
#define ND 64
#define NG 32
#define CPG 16
#define SCALE_Q 0.18033688f  /* 0.125 * log2(e): softmax runs in exp2 domain */

__device__ __forceinline__ u16 f2bf(float x) {
  u32 u = __builtin_bit_cast(u32, x);
  u = u + 0x7fffu + ((u >> 16) & 1u);
  return (u16)(u >> 16);
}

__device__ __forceinline__ float exp2_fast(float x) {
  float r;
  asm("v_exp_f32 %0, %1" : "=v"(r) : "v"(x));
  return r;
}

__device__ __forceinline__ u32 cvtpk_bf16(float lo, float hi) {
  u32 r;
  asm("v_cvt_pk_bf16_f32 %0, %1, %2" : "=v"(r) : "v"(lo), "v"(hi));
  return r;
}

__device__ __forceinline__ void gll16(void* l, const void* g) {
  __builtin_amdgcn_global_load_lds((const __attribute__((address_space(1))) void*)g,
                                   (__attribute__((address_space(3))) void*)l, 16, 0, 0);
}

__device__ __forceinline__ void drain_vm() {
  asm volatile("s_waitcnt vmcnt(0)" ::: "memory");
}

__device__ __forceinline__ void wait_vm4() {
  asm volatile("s_waitcnt vmcnt(4)" ::: "memory");
}

__device__ __forceinline__ void wait_vm8() {
  asm volatile("s_waitcnt vmcnt(8)" ::: "memory");
}

// ---------------- K1: GroupNorm -> xnT (single-pass) + fused weight fp32->bf16
__global__ __launch_bounds__(1024) void gn_kernel(const float* __restrict__ x,
                                                  const float* __restrict__ gamma,
                                                  const float* __restrict__ beta,
                                                  u16* __restrict__ xnT,
                                                  const float* __restrict__ qkvw,
                                                  const float* __restrict__ outw,
                                                  u16* __restrict__ wq,
                                                  u16* __restrict__ wo) {
  __shared__ float red[34];
  const int t = threadIdx.x;
  const int wave = t >> 6, lane = t & 63;
  const int b = blockIdx.x >> 5, g = blockIdx.x & 31;
  const float* xb = x + (size_t)(b * NC + g * CPG) * NS;
  const int p4 = t >> 2;
  const int cq = (t & 3) * 4;

  // fused weight conversion: block i converts float range [i*4096, (i+1)*4096)
  {
    int blk = blockIdx.x;
    const float* src = (blk < 192) ? qkvw : outw;
    u16* dst = (blk < 192) ? wq : wo;
    int off = ((blk < 192) ? blk * 4096 : (blk - 192) * 4096) + t * 4;
    float4 v = *(const float4*)(src + off);
    u32 lo = (u32)f2bf(v.x) | ((u32)f2bf(v.y) << 16);
    u32 hi = (u32)f2bf(v.z) | ((u32)f2bf(v.w) << 16);
    u32* p = (u32*)(dst + off);
    p[0] = lo; p[1] = hi;
  }

  float4 hold[4];
  float s = 0.f, ss = 0.f;
#pragma unroll
  for (int i = 0; i < 4; ++i) {
    float4 v = ((const float4*)xb)[(cq + i) * 256 + p4];
    hold[i] = v;
    s  += (v.x + v.y) + (v.z + v.w);
    ss += (v.x * v.x + v.y * v.y) + (v.z * v.z + v.w * v.w);
  }
#pragma unroll
  for (int m2 = 32; m2; m2 >>= 1) { s += __shfl_xor(s, m2); ss += __shfl_xor(ss, m2); }
  if (lane == 0) { red[wave] = s; red[16 + wave] = ss; }
  __syncthreads();
  if (t == 0) {
    float fs = 0.f, fss = 0.f;
#pragma unroll
    for (int w = 0; w < 16; ++w) { fs += red[w]; fss += red[16 + w]; }
    float mean = fs * (1.f / 16384.f);
    float var  = fss * (1.f / 16384.f) - mean * mean;
    red[32] = mean;
    red[33] = rsqrtf(fmaxf(var, 0.f) + 1e-5f);
  }
  __syncthreads();
  const float mean = red[32], inv = red[33];
  float gm[4], bt[4];
#pragma unroll
  for (int i = 0; i < 4; ++i) {
    float ga = gamma[g * CPG + cq + i];
    gm[i] = ga * inv;
    bt[i] = beta[g * CPG + cq + i] - mean * inv * ga;
  }
  float y0[4], y1[4], y2[4], y3[4];
#pragma unroll
  for (int i = 0; i < 4; ++i) {
    float4 v = hold[i];
    y0[i] = v.x * gm[i] + bt[i];
    y1[i] = v.y * gm[i] + bt[i];
    y2[i] = v.z * gm[i] + bt[i];
    y3[i] = v.w * gm[i] + bt[i];
  }
  u32 pk[4][2];
  pk[0][0] = (u32)f2bf(y0[0]) | ((u32)f2bf(y0[1]) << 16);
  pk[0][1] = (u32)f2bf(y0[2]) | ((u32)f2bf(y0[3]) << 16);
  pk[1][0] = (u32)f2bf(y1[0]) | ((u32)f2bf(y1[1]) << 16);
  pk[1][1] = (u32)f2bf(y1[2]) | ((u32)f2bf(y1[3]) << 16);
  pk[2][0] = (u32)f2bf(y2[0]) | ((u32)f2bf(y2[1]) << 16);
  pk[2][1] = (u32)f2bf(y2[2]) | ((u32)f2bf(y2[3]) << 16);
  pk[3][0] = (u32)f2bf(y3[0]) | ((u32)f2bf(y3[1]) << 16);
  pk[3][1] = (u32)f2bf(y3[2]) | ((u32)f2bf(y3[3]) << 16);
#pragma unroll
  for (int j = 0; j < 4; ++j) {
    u32* dst = (u32*)(xnT + (size_t)(b * NS + p4 * 4 + j) * NC + g * CPG + cq);
    dst[0] = pk[j][0];
    dst[1] = pk[j][1];
  }
}

// ---------------- K2: QKV gemm_bt (counted-vmcnt 2-barrier pipeline) --------
__global__ __launch_bounds__(256) void qkv_gemm(const u16* __restrict__ A,
                                                const u16* __restrict__ BT,
                                                const float* __restrict__ bias,
                                                u16* __restrict__ qb,
                                                u16* __restrict__ kb,
                                                u16* __restrict__ vb) {
  __shared__ char lds[32768];  // 2 x (A 8KB + B 8KB)
  const int t = threadIdx.x, wave = t >> 6, lane = t & 63;
  int lin = blockIdx.x;
  int swz = (lin & 7) * 96 + (lin >> 3);
  const int bn = (swz & 7) * 128;
  const int bm = ((swz >> 3) % 12) * 128;
  const int bb = swz / 96;
  const u16* Bt = BT + (size_t)bb * NS * NC;
  const int wm = wave >> 1, wn = wave & 1;
  f32x4 acc[4][4];
#pragma unroll
  for (int i = 0; i < 4; ++i)
#pragma unroll
    for (int j = 0; j < 4; ++j) acc[i][j] = (f32x4){0.f, 0.f, 0.f, 0.f};

  int c0 = t, c1 = 256 + t;
  int r0c = c0 >> 2, r1c = c1 >> 2;
  int h0 = (c0 & 3) ^ ((c0 >> 3) & 3), h1 = (c1 & 3) ^ ((c1 >> 3) & 3);
  const u16* a0 = A  + (size_t)(bm + r0c) * NC + h0 * 8;
  const u16* a1 = A  + (size_t)(bm + r1c) * NC + h1 * 8;
  const u16* b0 = Bt + (size_t)(bn + r0c) * NC + h0 * 8;
  const u16* b1 = Bt + (size_t)(bn + r1c) * NC + h1 * 8;

  // prologue: stage k-step 0, full drain
  gll16(lds + c0 * 16, a0); gll16(lds + c1 * 16, a1);
  gll16(lds + 8192 + c0 * 16, b0); gll16(lds + 8192 + c1 * 16, b1);
  drain_vm();
  __syncthreads();

  for (int ks = 0; ks < 16; ++ks) {
    const char* cur = lds + ((ks & 1) << 14);
    if (ks < 15) {
      char* nxt = lds + (((ks + 1) & 1) << 14);
      int ko = (ks + 1) * 32;
      gll16(nxt + c0 * 16,        a0 + ko);
      gll16(nxt + c1 * 16,        a1 + ko);
      gll16(nxt + 8192 + c0 * 16, b0 + ko);
      gll16(nxt + 8192 + c1 * 16, b1 + ko);
      wait_vm4();   // own loads(ks) landed; loads(ks+1) stay in flight (T4)
    } else {
      drain_vm();
    }
    __builtin_amdgcn_s_barrier();
    __builtin_amdgcn_sched_barrier(0);
    bf16x8 af[4], bfr[4];
#pragma unroll
    for (int mf = 0; mf < 4; ++mf) {
      int row = wm * 64 + mf * 16 + (lane & 15);
      int cb = ((lane >> 4) * 16) ^ (((row >> 1) & 3) << 4);
      af[mf] = *(const bf16x8*)(cur + row * 64 + cb);
    }
#pragma unroll
    for (int nf = 0; nf < 4; ++nf) {
      int row = wn * 64 + nf * 16 + (lane & 15);
      int cb = ((lane >> 4) * 16) ^ (((row >> 1) & 3) << 4);
      bfr[nf] = *(const bf16x8*)(cur + 8192 + row * 64 + cb);
    }
#pragma unroll
    for (int mf = 0; mf < 4; ++mf)
#pragma unroll
      for (int nf = 0; nf < 4; ++nf)
        acc[mf][nf] = __builtin_amdgcn_mfma_f32_16x16x32_bf16(af[mf], bfr[nf], acc[mf][nf], 0, 0, 0);
    __builtin_amdgcn_s_barrier();
  }
  // packed epilogue: quad j=0..3 -> consecutive r at fixed p (8B stores for Q/K)
  const int pbase = bn + wn * 64 + (lane & 15);
#pragma unroll
  for (int mf = 0; mf < 4; ++mf) {
    int o0 = bm + wm * 64 + mf * 16 + (lane >> 4) * 4;
    int n = o0 / 192;
    int r0 = o0 - n * 192;
    float4 bv = *(const float4*)(bias + o0);
    size_t hb = (size_t)(bb * NH + n);
#pragma unroll
    for (int nf = 0; nf < 4; ++nf) {
      int p = pbase + nf * 16;
      float v0 = acc[mf][nf][0] + bv.x;
      float v1 = acc[mf][nf][1] + bv.y;
      float v2 = acc[mf][nf][2] + bv.z;
      float v3 = acc[mf][nf][3] + bv.w;
      if (r0 < 64) {
        u32x2 w;
        w[0] = cvtpk_bf16(v0 * SCALE_Q, v1 * SCALE_Q);
        w[1] = cvtpk_bf16(v2 * SCALE_Q, v3 * SCALE_Q);
        *(u32x2*)(qb + (hb * NS + p) * ND + r0) = w;
      } else if (r0 < 128) {
        u32x2 w;
        w[0] = cvtpk_bf16(v0, v1);
        w[1] = cvtpk_bf16(v2, v3);
        *(u32x2*)(kb + (hb * NS + p) * ND + (r0 - 64)) = w;
      } else {
        vb[(hb * ND + (r0 - 128) + 0) * NS + p] = f2bf(v0);
        vb[(hb * ND + (r0 - 128) + 1) * NS + p] = f2bf(v1);
        vb[(hb * ND + (r0 - 128) + 2) * NS + p] = f2bf(v2);
        vb[(hb * ND + (r0 - 128) + 3) * NS + p] = f2bf(v3);
      }
    }
  }
}

// ---------------- K3: flash attention (counted-vmcnt 2-barrier pipeline) -----
// R16's T4 pattern ported: 8 gll16/thread/iter -> wait vmcnt(8) keeps next
// tile-pair's loads in flight across the barrier.
__global__ __launch_bounds__(256) void attn_kernel(const u16* __restrict__ qbuf,
                                                   const u16* __restrict__ kbuf,
                                                   const u16* __restrict__ vbuf,
                                                   u16* __restrict__ aoT) {
  __shared__ char lds[65536];  // 2 x (K0 8K | V0 8K | K1 8K | V1 8K)
  const int t = threadIdx.x, wave = t >> 6, lane = t & 63;
  int lin = blockIdx.x;
  int swz = (lin & 7) * 64 + (lin >> 3);
  const int qblk = swz & 7;
  const int bn = swz >> 3;
  const int b = bn >> 3, n = bn & 7;
  const u16* qp = qbuf + (size_t)bn * NS * ND;
  const char* kpb = (const char*)(kbuf + (size_t)bn * NS * ND);
  const char* vpb = (const char*)(vbuf + (size_t)bn * ND * NS);
  const int g = lane >> 4, q = lane & 15;
  const int qrowbase = qblk * 128 + wave * 32;

  bf16x8 bq[2][2];
#pragma unroll
  for (int qf = 0; qf < 2; ++qf) {
    const u16* qr = qp + (size_t)(qrowbase + qf * 16 + q) * ND + g * 8;
    bq[qf][0] = *(const bf16x8*)(qr);
    bq[qf][1] = *(const bf16x8*)(qr + 32);
  }
  // all-ones A fragment (bf16 1.0 = 0x3F80) for the l row-sum MFMA
  u32x4 onesw;
  onesw[0] = 0x3F803F80u; onesw[1] = 0x3F803F80u;
  onesw[2] = 0x3F803F80u; onesw[3] = 0x3F803F80u;
  const bf16x8 ones = __builtin_bit_cast(bf16x8, onesw);

  int c0 = t, c1 = 256 + t;
  int lam0 = c0 >> 3, lam1 = c1 >> 3;
  int chs0 = (c0 & 7) ^ (lam0 & 7), chs1 = (c1 & 7) ^ (lam1 & 7);
  int kv0 = ((lam0 >> 5) & 1) * 32 + ((lam0 >> 4) & 1) * 4 + ((lam0 >> 2) & 3) * 8 + (lam0 & 3);
  int kv1 = ((lam1 >> 5) & 1) * 32 + ((lam1 >> 4) & 1) * 4 + ((lam1 >> 2) & 3) * 8 + (lam1 & 3);
  const char* ksrc0 = kpb + kv0 * 128 + chs0 * 16;
  const char* ksrc1 = kpb + kv1 * 128 + chs1 * 16;
  const char* vsrc0 = vpb + lam0 * 2048 + chs0 * 16;
  const char* vsrc1 = vpb + lam1 * 2048 + chs1 * 16;
  const int koffA = q * 128 + (((0 * 4 + g) ^ (q & 7)) << 4);
  const int koffB = q * 128 + (((1 * 4 + g) ^ (q & 7)) << 4);

  f32x4 lacc[2];
  f32x4 oacc[4][2];  // [df][qf]
  lacc[0] = (f32x4){0.f, 0.f, 0.f, 0.f};
  lacc[1] = (f32x4){0.f, 0.f, 0.f, 0.f};
#pragma unroll
  for (int df = 0; df < 4; ++df)
#pragma unroll
    for (int qf = 0; qf < 2; ++qf) oacc[df][qf] = (f32x4){0.f, 0.f, 0.f, 0.f};

  // prologue: stage tile pair {0,1} into buffer 0, full drain
#pragma unroll
  for (int sst = 0; sst < 2; ++sst) {
    char* dst = lds + sst * 16384;
    gll16(dst + c0 * 16,        ksrc0 + (size_t)sst * 8192);
    gll16(dst + c1 * 16,        ksrc1 + (size_t)sst * 8192);
    gll16(dst + 8192 + c0 * 16, vsrc0 + (size_t)sst * 128);
    gll16(dst + 8192 + c1 * 16, vsrc1 + (size_t)sst * 128);
  }
  drain_vm();
  __syncthreads();

  for (int j = 0; j < 8; ++j) {
    const char* cur = lds + (j & 1) * 32768;
    if (j < 7) {
      char* nxt = lds + ((j + 1) & 1) * 32768;
#pragma unroll
      for (int sst = 0; sst < 2; ++sst) {
        int kb = 2 * (j + 1) + sst;
        char* dst = nxt + sst * 16384;
        gll16(dst + c0 * 16,        ksrc0 + (size_t)kb * 8192);
        gll16(dst + c1 * 16,        ksrc1 + (size_t)kb * 8192);
        gll16(dst + 8192 + c0 * 16, vsrc0 + (size_t)kb * 128);
        gll16(dst + 8192 + c1 * 16, vsrc1 + (size_t)kb * 128);
      }
      wait_vm8();   // own loads(j) landed (issued a full iter ago); 8 newest in flight
    } else {
      drain_vm();   // last tile pair
    }
    __builtin_amdgcn_s_barrier();        // all waves' loads(j) landed
    __builtin_amdgcn_sched_barrier(0);   // rule #18: pin LDS reads below barrier
#pragma unroll
    for (int sst = 0; sst < 2; ++sst) {
      const char* curs = cur + sst * 16384;
      bf16x8 kf0[4], kf1[4];
#pragma unroll
      for (int cf = 0; cf < 4; ++cf) {
        kf0[cf] = *(const bf16x8*)(curs + cf * 2048 + koffA);
        kf1[cf] = *(const bf16x8*)(curs + cf * 2048 + koffB);
      }
      f32x4 s[2][4];  // [qf][cf]
      __builtin_amdgcn_s_setprio(1);
#pragma unroll
      for (int qf = 0; qf < 2; ++qf)
#pragma unroll
        for (int cf = 0; cf < 4; ++cf) {
          f32x4 s0 = __builtin_amdgcn_mfma_f32_16x16x32_bf16(kf0[cf], bq[qf][0], (f32x4){0.f, 0.f, 0.f, 0.f}, 0, 0, 0);
          s[qf][cf] = __builtin_amdgcn_mfma_f32_16x16x32_bf16(kf1[cf], bq[qf][1], s0, 0, 0, 0);
        }
      __builtin_amdgcn_s_setprio(0);
      const char* curv = curs + 8192;
      bf16x8 vf0[4], vf1[4];
#pragma unroll
      for (int df = 0; df < 4; ++df) {
        vf0[df] = *(const bf16x8*)(curv + df * 2048 + koffA);
        vf1[df] = *(const bf16x8*)(curv + df * 2048 + koffB);
      }
#pragma unroll
      for (int qf = 0; qf < 2; ++qf) {
        f32x4 s0 = s[qf][0], s1 = s[qf][1], s2 = s[qf][2], s3 = s[qf][3];
        // P = exp2(S), no shift (ratio cancels exactly in O/l)
        u32x4 w0, w1;
        w0[0] = cvtpk_bf16(exp2_fast(s0[0]), exp2_fast(s0[1]));
        w0[1] = cvtpk_bf16(exp2_fast(s0[2]), exp2_fast(s0[3]));
        w0[2] = cvtpk_bf16(exp2_fast(s1[0]), exp2_fast(s1[1]));
        w0[3] = cvtpk_bf16(exp2_fast(s1[2]), exp2_fast(s1[3]));
        w1[0] = cvtpk_bf16(exp2_fast(s2[0]), exp2_fast(s2[1]));
        w1[1] = cvtpk_bf16(exp2_fast(s2[2]), exp2_fast(s2[3]));
        w1[2] = cvtpk_bf16(exp2_fast(s3[0]), exp2_fast(s3[1]));
        w1[3] = cvtpk_bf16(exp2_fast(s3[2]), exp2_fast(s3[3]));
        bf16x8 pb0 = __builtin_bit_cast(bf16x8, w0);
        bf16x8 pb1 = __builtin_bit_cast(bf16x8, w1);
        __builtin_amdgcn_s_setprio(1);
#pragma unroll
        for (int df = 0; df < 4; ++df) {
          oacc[df][qf] = __builtin_amdgcn_mfma_f32_16x16x32_bf16(vf0[df], pb0, oacc[df][qf], 0, 0, 0);
          oacc[df][qf] = __builtin_amdgcn_mfma_f32_16x16x32_bf16(vf1[df], pb1, oacc[df][qf], 0, 0, 0);
        }
        // l row-sum: ones-A MFMA sums P over all 32 k-slots (cross-lane complete)
        lacc[qf] = __builtin_amdgcn_mfma_f32_16x16x32_bf16(ones, pb0, lacc[qf], 0, 0, 0);
        lacc[qf] = __builtin_amdgcn_mfma_f32_16x16x32_bf16(ones, pb1, lacc[qf], 0, 0, 0);
        __builtin_amdgcn_s_setprio(0);
      }
    }
    __builtin_amdgcn_s_barrier();        // reads of cur done -> iter j+1 may overwrite
  }
  // epilogue: transpose via wave-private swizzled patch in buffer-0 K0 region.
  // Last compute (j=7) read buffer 1; all waves passed j=7's leading barrier,
  // so buffer 0 has no pending readers. Same-wave DS ordering covers write->read.
  char* myT = lds + wave * 2048;
#pragma unroll
  for (int qf = 0; qf < 2; ++qf) {
    const float inv = 1.f / lacc[qf][0];
#pragma unroll
    for (int df = 0; df < 4; ++df)
#pragma unroll
      for (int h = 0; h < 2; ++h) {
        u32 w = cvtpk_bf16(oacc[df][qf][2 * h] * inv, oacc[df][qf][2 * h + 1] * inv);
        int X = (df * 16 + 4 * g + 2 * h) * 2;
        *(u32*)(myT + q * 128 + (X ^ ((q & 7) << 4))) = w;
      }
#pragma unroll
    for (int h = 0; h < 2; ++h) {
      int q2 = h * 8 + (lane >> 3);
      int c = lane & 7;
      bf16x8 vrow = *(const bf16x8*)(myT + q2 * 128 + ((c * 16) ^ ((q2 & 7) << 4)));
      int prow = qrowbase + qf * 16 + q2;
      *(bf16x8*)(aoT + (size_t)(b * NS + prow) * NC + n * 64 + c * 8) = vrow;
    }
  }
}

// ---------------- K4: out gemm_bt (counted-vmcnt 2-barrier pipeline) ---------
__global__ __launch_bounds__(256) void out_gemm(const u16* __restrict__ A,
                                                const u16* __restrict__ BT,
                                                const float* __restrict__ bias,
                                                const float* __restrict__ xres,
                                                float* __restrict__ out) {
  __shared__ char lds[32768];
  const int t = threadIdx.x, wave = t >> 6, lane = t & 63;
  int lin = blockIdx.x;
  int swz = (lin & 7) * 32 + (lin >> 3);
  const int bn = (swz & 7) * 128;
  const int bm = ((swz >> 3) & 3) * 128;
  const int bb = swz >> 5;
  const u16* Bt = BT + (size_t)bb * NS * NC;
  const int wm = wave >> 1, wn = wave & 1;
  f32x4 acc[4][4];
#pragma unroll
  for (int i = 0; i < 4; ++i)
#pragma unroll
    for (int j = 0; j < 4; ++j) acc[i][j] = (f32x4){0.f, 0.f, 0.f, 0.f};

  int c0 = t, c1 = 256 + t;
  int r0 = c0 >> 2, r1 = c1 >> 2;
  int h0 = (c0 & 3) ^ ((c0 >> 3) & 3), h1 = (c1 & 3) ^ ((c1 >> 3) & 3);
  const u16* a0 = A  + (size_t)(bm + r0) * NC + h0 * 8;
  const u16* a1 = A  + (size_t)(bm + r1) * NC + h1 * 8;
  const u16* b0 = Bt + (size_t)(bn + r0) * NC + h0 * 8;
  const u16* b1 = Bt + (size_t)(bn + r1) * NC + h1 * 8;

  gll16(lds + c0 * 16, a0); gll16(lds + c1 * 16, a1);
  gll16(lds + 8192 + c0 * 16, b0); gll16(lds + 8192 + c1 * 16, b1);
  drain_vm();
  __syncthreads();

  for (int ks = 0; ks < 16; ++ks) {
    const char* cur = lds + ((ks & 1) << 14);
    if (ks < 15) {
      char* nxt = lds + (((ks + 1) & 1) << 14);
      int ko = (ks + 1) * 32;
      gll16(nxt + c0 * 16,        a0 + ko);
      gll16(nxt + c1 * 16,        a1 + ko);
      gll16(nxt + 8192 + c0 * 16, b0 + ko);
      gll16(nxt + 8192 + c1 * 16, b1 + ko);
      wait_vm4();
    } else {
      drain_vm();
    }
    __builtin_amdgcn_s_barrier();
    __builtin_amdgcn_sched_barrier(0);
    bf16x8 af[4], bfr[4];
#pragma unroll
    for (int mf = 0; mf < 4; ++mf) {
      int row = wm * 64 + mf * 16 + (lane & 15);
      int cb = ((lane >> 4) * 16) ^ (((row >> 1) & 3) << 4);
      af[mf] = *(const bf16x8*)(cur + row * 64 + cb);
    }
#pragma unroll
    for (int nf = 0; nf < 4; ++nf) {
      int row = wn * 64 + nf * 16 + (lane & 15);
      int cb = ((lane >> 4) * 16) ^ (((row >> 1) & 3) << 4);
      bfr[nf] = *(const bf16x8*)(cur + 8192 + row * 64 + cb);
    }
#pragma unroll
    for (int mf = 0; mf < 4; ++mf)
#pragma unroll
      for (int nf = 0; nf < 4; ++nf)
        acc[mf][nf] = __builtin_amdgcn_mfma_f32_16x16x32_bf16(af[mf], bfr[nf], acc[mf][nf], 0, 0, 0);
    __builtin_amdgcn_s_barrier();
  }
#pragma unroll
  for (int mf = 0; mf < 4; ++mf) {
#pragma unroll
    for (int j = 0; j < 4; ++j) {
      int o = bm + wm * 64 + mf * 16 + (lane >> 4) * 4 + j;
      float bv = bias[o];
#pragma unroll
      for (int nf = 0; nf < 4; ++nf) {
        int p = bn + wn * 64 + nf * 16 + (lane & 15);
        size_t idx = (size_t)(bb * NC + o) * NS + p;
        out[idx] = acc[mf][nf][j] + bv + xres[idx];
      }
    }
  }
}

extern "C" void kernel_launch(void* const* d_in, const int* in_sizes, int n_in,
                              void* d_out, int out_size, void* d_ws, size_t ws_size,
                              hipStream_t stream) {
  const float* x     = (const float*)d_in[0];
  const float* gn_w  = (const float*)d_in[1];
  const float* gn_b  = (const float*)d_in[2];
  const float* qkv_w = (const float*)d_in[3];
  const float* qkv_b = (const float*)d_in[4];
  const float* out_w = (const float*)d_in[5];
  const float* out_b = (const float*)d_in[6];
  float* out = (float*)d_out;
  char* ws = (char*)d_ws;

  u16* wq  = (u16*)(ws);
  u16* wo  = (u16*)(ws + 1572864);
  u16* xnT = (u16*)(ws + 2097152);
  u16* kb  = (u16*)(ws + 10485760);
  u16* vb  = (u16*)(ws + 18874368);
  u16* aoT = (u16*)(ws + 2097152);   // overlaps xnT (sequentially dead)
  u16* qb  = (u16*)d_out;            // scratch use of d_out; overwritten by out_gemm

  gn_kernel<<<dim3(NB * NG), dim3(1024), 0, stream>>>(x, gn_w, gn_b, xnT, qkv_w, out_w, wq, wo);
  qkv_gemm<<<dim3(768), dim3(256), 0, stream>>>(wq, xnT, qkv_b, qb, kb, vb);
  attn_kernel<<<dim3(512), dim3(256), 0, stream>>>(qb, kb, vb, aoT);
  out_gemm<<<dim3(256), dim3(256), 0, stream>>>(wo, aoT, out_b, x, out);
}

// Round 19
// 69.526 us; speedup vs baseline: 1.0075x; 1.0075x over previous
//
#include <hip/hip_runtime.h>
#include <math.h>

typedef unsigned short u16;
typedef unsigned int   u32;
typedef __attribute__((ext_vector_type(8))) short bf16x8;
typedef __attribute__((ext_vector_type(4))) float f32x4;
typedef __attribute__((ext_vector_type(4))) u32   u32x4;
typedef __attribute__((ext_vector_type(2))) u32   u32x2;

#define NB 8
#define NC 512
#define NS 1024
#define NH 8
#define ND 64
#define NG 32
#define CPG 16
#define SCALE_Q 0.18033688f  /* 0.125 * log2(e): softmax runs in exp2 domain */

__device__ __forceinline__ u16 f2bf(float x) {
  u32 u = __builtin_bit_cast(u32, x);
  u = u + 0x7fffu + ((u >> 16) & 1u);
  return (u16)(u >> 16);
}

__device__ __forceinline__ float exp2_fast(float x) {
  float r;
  asm("v_exp_f32 %0, %1" : "=v"(r) : "v"(x));
  return r;
}

__device__ __forceinline__ u32 cvtpk_bf16(float lo, float hi) {
  u32 r;
  asm("v_cvt_pk_bf16_f32 %0, %1, %2" : "=v"(r) : "v"(lo), "v"(hi));
  return r;
}

__device__ __forceinline__ void gll16(void* l, const void* g) {
  __builtin_amdgcn_global_load_lds((const __attribute__((address_space(1))) void*)g,
                                   (__attribute__((address_space(3))) void*)l, 16, 0, 0);
}

__device__ __forceinline__ void drain_vm() {
  asm volatile("s_waitcnt vmcnt(0)" ::: "memory");
}

__device__ __forceinline__ void wait_vm4() {
  asm volatile("s_waitcnt vmcnt(4)" ::: "memory");
}

// ---------------- K1: GroupNorm -> xnT (single-pass) + fused weight fp32->bf16
__global__ __launch_bounds__(1024) void gn_kernel(const float* __restrict__ x,
                                                  const float* __restrict__ gamma,
                                                  const float* __restrict__ beta,
                                                  u16* __restrict__ xnT,
                                                  const float* __restrict__ qkvw,
                                                  const float* __restrict__ outw,
                                                  u16* __restrict__ wq,
                                                  u16* __restrict__ wo) {
  __shared__ float red[34];
  const int t = threadIdx.x;
  const int wave = t >> 6, lane = t & 63;
  const int b = blockIdx.x >> 5, g = blockIdx.x & 31;
  const float* xb = x + (size_t)(b * NC + g * CPG) * NS;
  const int p4 = t >> 2;
  const int cq = (t & 3) * 4;

  // fused weight conversion: block i converts float range [i*4096, (i+1)*4096)
  {
    int blk = blockIdx.x;
    const float* src = (blk < 192) ? qkvw : outw;
    u16* dst = (blk < 192) ? wq : wo;
    int off = ((blk < 192) ? blk * 4096 : (blk - 192) * 4096) + t * 4;
    float4 v = *(const float4*)(src + off);
    u32 lo = (u32)f2bf(v.x) | ((u32)f2bf(v.y) << 16);
    u32 hi = (u32)f2bf(v.z) | ((u32)f2bf(v.w) << 16);
    u32* p = (u32*)(dst + off);
    p[0] = lo; p[1] = hi;
  }

  float4 hold[4];
  float s = 0.f, ss = 0.f;
#pragma unroll
  for (int i = 0; i < 4; ++i) {
    float4 v = ((const float4*)xb)[(cq + i) * 256 + p4];
    hold[i] = v;
    s  += (v.x + v.y) + (v.z + v.w);
    ss += (v.x * v.x + v.y * v.y) + (v.z * v.z + v.w * v.w);
  }
#pragma unroll
  for (int m2 = 32; m2; m2 >>= 1) { s += __shfl_xor(s, m2); ss += __shfl_xor(ss, m2); }
  if (lane == 0) { red[wave] = s; red[16 + wave] = ss; }
  __syncthreads();
  if (t == 0) {
    float fs = 0.f, fss = 0.f;
#pragma unroll
    for (int w = 0; w < 16; ++w) { fs += red[w]; fss += red[16 + w]; }
    float mean = fs * (1.f / 16384.f);
    float var  = fss * (1.f / 16384.f) - mean * mean;
    red[32] = mean;
    red[33] = rsqrtf(fmaxf(var, 0.f) + 1e-5f);
  }
  __syncthreads();
  const float mean = red[32], inv = red[33];
  float gm[4], bt[4];
#pragma unroll
  for (int i = 0; i < 4; ++i) {
    float ga = gamma[g * CPG + cq + i];
    gm[i] = ga * inv;
    bt[i] = beta[g * CPG + cq + i] - mean * inv * ga;
  }
  float y0[4], y1[4], y2[4], y3[4];
#pragma unroll
  for (int i = 0; i < 4; ++i) {
    float4 v = hold[i];
    y0[i] = v.x * gm[i] + bt[i];
    y1[i] = v.y * gm[i] + bt[i];
    y2[i] = v.z * gm[i] + bt[i];
    y3[i] = v.w * gm[i] + bt[i];
  }
  u32 pk[4][2];
  pk[0][0] = (u32)f2bf(y0[0]) | ((u32)f2bf(y0[1]) << 16);
  pk[0][1] = (u32)f2bf(y0[2]) | ((u32)f2bf(y0[3]) << 16);
  pk[1][0] = (u32)f2bf(y1[0]) | ((u32)f2bf(y1[1]) << 16);
  pk[1][1] = (u32)f2bf(y1[2]) | ((u32)f2bf(y1[3]) << 16);
  pk[2][0] = (u32)f2bf(y2[0]) | ((u32)f2bf(y2[1]) << 16);
  pk[2][1] = (u32)f2bf(y2[2]) | ((u32)f2bf(y2[3]) << 16);
  pk[3][0] = (u32)f2bf(y3[0]) | ((u32)f2bf(y3[1]) << 16);
  pk[3][1] = (u32)f2bf(y3[2]) | ((u32)f2bf(y3[3]) << 16);
#pragma unroll
  for (int j = 0; j < 4; ++j) {
    u32* dst = (u32*)(xnT + (size_t)(b * NS + p4 * 4 + j) * NC + g * CPG + cq);
    dst[0] = pk[j][0];
    dst[1] = pk[j][1];
  }
}

// ---------------- K2: QKV gemm_bt (counted-vmcnt 2-barrier pipeline) --------
__global__ __launch_bounds__(256) void qkv_gemm(const u16* __restrict__ A,
                                                const u16* __restrict__ BT,
                                                const float* __restrict__ bias,
                                                u16* __restrict__ qb,
                                                u16* __restrict__ kb,
                                                u16* __restrict__ vb) {
  __shared__ char lds[32768];  // 2 x (A 8KB + B 8KB)
  const int t = threadIdx.x, wave = t >> 6, lane = t & 63;
  int lin = blockIdx.x;
  int swz = (lin & 7) * 96 + (lin >> 3);
  const int bn = (swz & 7) * 128;
  const int bm = ((swz >> 3) % 12) * 128;
  const int bb = swz / 96;
  const u16* Bt = BT + (size_t)bb * NS * NC;
  const int wm = wave >> 1, wn = wave & 1;
  f32x4 acc[4][4];
#pragma unroll
  for (int i = 0; i < 4; ++i)
#pragma unroll
    for (int j = 0; j < 4; ++j) acc[i][j] = (f32x4){0.f, 0.f, 0.f, 0.f};

  int c0 = t, c1 = 256 + t;
  int r0c = c0 >> 2, r1c = c1 >> 2;
  int h0 = (c0 & 3) ^ ((c0 >> 3) & 3), h1 = (c1 & 3) ^ ((c1 >> 3) & 3);
  const u16* a0 = A  + (size_t)(bm + r0c) * NC + h0 * 8;
  const u16* a1 = A  + (size_t)(bm + r1c) * NC + h1 * 8;
  const u16* b0 = Bt + (size_t)(bn + r0c) * NC + h0 * 8;
  const u16* b1 = Bt + (size_t)(bn + r1c) * NC + h1 * 8;

  // prologue: stage k-step 0, full drain
  gll16(lds + c0 * 16, a0); gll16(lds + c1 * 16, a1);
  gll16(lds + 8192 + c0 * 16, b0); gll16(lds + 8192 + c1 * 16, b1);
  drain_vm();
  __syncthreads();

  for (int ks = 0; ks < 16; ++ks) {
    const char* cur = lds + ((ks & 1) << 14);
    if (ks < 15) {
      char* nxt = lds + (((ks + 1) & 1) << 14);
      int ko = (ks + 1) * 32;
      gll16(nxt + c0 * 16,        a0 + ko);
      gll16(nxt + c1 * 16,        a1 + ko);
      gll16(nxt + 8192 + c0 * 16, b0 + ko);
      gll16(nxt + 8192 + c1 * 16, b1 + ko);
      wait_vm4();   // own loads(ks) landed; loads(ks+1) stay in flight (T4)
    } else {
      drain_vm();
    }
    __builtin_amdgcn_s_barrier();
    __builtin_amdgcn_sched_barrier(0);
    bf16x8 af[4], bfr[4];
#pragma unroll
    for (int mf = 0; mf < 4; ++mf) {
      int row = wm * 64 + mf * 16 + (lane & 15);
      int cb = ((lane >> 4) * 16) ^ (((row >> 1) & 3) << 4);
      af[mf] = *(const bf16x8*)(cur + row * 64 + cb);
    }
#pragma unroll
    for (int nf = 0; nf < 4; ++nf) {
      int row = wn * 64 + nf * 16 + (lane & 15);
      int cb = ((lane >> 4) * 16) ^ (((row >> 1) & 3) << 4);
      bfr[nf] = *(const bf16x8*)(cur + 8192 + row * 64 + cb);
    }
#pragma unroll
    for (int mf = 0; mf < 4; ++mf)
#pragma unroll
      for (int nf = 0; nf < 4; ++nf)
        acc[mf][nf] = __builtin_amdgcn_mfma_f32_16x16x32_bf16(af[mf], bfr[nf], acc[mf][nf], 0, 0, 0);
    __builtin_amdgcn_s_barrier();
  }
  // packed epilogue: quad j=0..3 -> consecutive r at fixed p (8B stores for Q/K)
  const int pbase = bn + wn * 64 + (lane & 15);
#pragma unroll
  for (int mf = 0; mf < 4; ++mf) {
    int o0 = bm + wm * 64 + mf * 16 + (lane >> 4) * 4;
    int n = o0 / 192;
    int r0 = o0 - n * 192;
    float4 bv = *(const float4*)(bias + o0);
    size_t hb = (size_t)(bb * NH + n);
#pragma unroll
    for (int nf = 0; nf < 4; ++nf) {
      int p = pbase + nf * 16;
      float v0 = acc[mf][nf][0] + bv.x;
      float v1 = acc[mf][nf][1] + bv.y;
      float v2 = acc[mf][nf][2] + bv.z;
      float v3 = acc[mf][nf][3] + bv.w;
      if (r0 < 64) {
        u32x2 w;
        w[0] = cvtpk_bf16(v0 * SCALE_Q, v1 * SCALE_Q);
        w[1] = cvtpk_bf16(v2 * SCALE_Q, v3 * SCALE_Q);
        *(u32x2*)(qb + (hb * NS + p) * ND + r0) = w;
      } else if (r0 < 128) {
        u32x2 w;
        w[0] = cvtpk_bf16(v0, v1);
        w[1] = cvtpk_bf16(v2, v3);
        *(u32x2*)(kb + (hb * NS + p) * ND + (r0 - 64)) = w;
      } else {
        vb[(hb * ND + (r0 - 128) + 0) * NS + p] = f2bf(v0);
        vb[(hb * ND + (r0 - 128) + 1) * NS + p] = f2bf(v1);
        vb[(hb * ND + (r0 - 128) + 2) * NS + p] = f2bf(v2);
        vb[(hb * ND + (r0 - 128) + 3) * NS + p] = f2bf(v3);
      }
    }
  }
}

// ---------------- K3: flash attention (R13-exact: QBLK=32, KVBLK=128) --------
__global__ __launch_bounds__(256) void attn_kernel(const u16* __restrict__ qbuf,
                                                   const u16* __restrict__ kbuf,
                                                   const u16* __restrict__ vbuf,
                                                   u16* __restrict__ aoT) {
  __shared__ char lds[65536];  // 2 x (K0 8K | V0 8K | K1 8K | V1 8K)
  const int t = threadIdx.x, wave = t >> 6, lane = t & 63;
  int lin = blockIdx.x;
  int swz = (lin & 7) * 64 + (lin >> 3);
  const int qblk = swz & 7;
  const int bn = swz >> 3;
  const int b = bn >> 3, n = bn & 7;
  const u16* qp = qbuf + (size_t)bn * NS * ND;
  const char* kpb = (const char*)(kbuf + (size_t)bn * NS * ND);
  const char* vpb = (const char*)(vbuf + (size_t)bn * ND * NS);
  const int g = lane >> 4, q = lane & 15;
  const int qrowbase = qblk * 128 + wave * 32;

  bf16x8 bq[2][2];
#pragma unroll
  for (int qf = 0; qf < 2; ++qf) {
    const u16* qr = qp + (size_t)(qrowbase + qf * 16 + q) * ND + g * 8;
    bq[qf][0] = *(const bf16x8*)(qr);
    bq[qf][1] = *(const bf16x8*)(qr + 32);
  }
  // all-ones A fragment (bf16 1.0 = 0x3F80) for the l row-sum MFMA
  u32x4 onesw;
  onesw[0] = 0x3F803F80u; onesw[1] = 0x3F803F80u;
  onesw[2] = 0x3F803F80u; onesw[3] = 0x3F803F80u;
  const bf16x8 ones = __builtin_bit_cast(bf16x8, onesw);

  int c0 = t, c1 = 256 + t;
  int lam0 = c0 >> 3, lam1 = c1 >> 3;
  int chs0 = (c0 & 7) ^ (lam0 & 7), chs1 = (c1 & 7) ^ (lam1 & 7);
  int kv0 = ((lam0 >> 5) & 1) * 32 + ((lam0 >> 4) & 1) * 4 + ((lam0 >> 2) & 3) * 8 + (lam0 & 3);
  int kv1 = ((lam1 >> 5) & 1) * 32 + ((lam1 >> 4) & 1) * 4 + ((lam1 >> 2) & 3) * 8 + (lam1 & 3);
  const char* ksrc0 = kpb + kv0 * 128 + chs0 * 16;
  const char* ksrc1 = kpb + kv1 * 128 + chs1 * 16;
  const char* vsrc0 = vpb + lam0 * 2048 + chs0 * 16;
  const char* vsrc1 = vpb + lam1 * 2048 + chs1 * 16;
  const int koffA = q * 128 + (((0 * 4 + g) ^ (q & 7)) << 4);
  const int koffB = q * 128 + (((1 * 4 + g) ^ (q & 7)) << 4);

  f32x4 lacc[2];
  f32x4 oacc[4][2];  // [df][qf]
  lacc[0] = (f32x4){0.f, 0.f, 0.f, 0.f};
  lacc[1] = (f32x4){0.f, 0.f, 0.f, 0.f};
#pragma unroll
  for (int df = 0; df < 4; ++df)
#pragma unroll
    for (int qf = 0; qf < 2; ++qf) oacc[df][qf] = (f32x4){0.f, 0.f, 0.f, 0.f};

  // prologue: stage tile pair {0,1} into buffer 0
#pragma unroll
  for (int sst = 0; sst < 2; ++sst) {
    char* dst = lds + sst * 16384;
    gll16(dst + c0 * 16,        ksrc0 + (size_t)sst * 8192);
    gll16(dst + c1 * 16,        ksrc1 + (size_t)sst * 8192);
    gll16(dst + 8192 + c0 * 16, vsrc0 + (size_t)sst * 128);
    gll16(dst + 8192 + c1 * 16, vsrc1 + (size_t)sst * 128);
  }
  drain_vm();
  __syncthreads();

  for (int j = 0; j < 8; ++j) {
    const char* cur = lds + (j & 1) * 32768;
    if (j < 7) {
      char* nxt = lds + ((j + 1) & 1) * 32768;
#pragma unroll
      for (int sst = 0; sst < 2; ++sst) {
        int kb = 2 * (j + 1) + sst;
        char* dst = nxt + sst * 16384;
        gll16(dst + c0 * 16,        ksrc0 + (size_t)kb * 8192);
        gll16(dst + c1 * 16,        ksrc1 + (size_t)kb * 8192);
        gll16(dst + 8192 + c0 * 16, vsrc0 + (size_t)kb * 128);
        gll16(dst + 8192 + c1 * 16, vsrc1 + (size_t)kb * 128);
      }
    }
#pragma unroll
    for (int sst = 0; sst < 2; ++sst) {
      const char* curs = cur + sst * 16384;
      bf16x8 kf0[4], kf1[4];
#pragma unroll
      for (int cf = 0; cf < 4; ++cf) {
        kf0[cf] = *(const bf16x8*)(curs + cf * 2048 + koffA);
        kf1[cf] = *(const bf16x8*)(curs + cf * 2048 + koffB);
      }
      f32x4 s[2][4];  // [qf][cf]
      __builtin_amdgcn_s_setprio(1);
#pragma unroll
      for (int qf = 0; qf < 2; ++qf)
#pragma unroll
        for (int cf = 0; cf < 4; ++cf) {
          f32x4 s0 = __builtin_amdgcn_mfma_f32_16x16x32_bf16(kf0[cf], bq[qf][0], (f32x4){0.f, 0.f, 0.f, 0.f}, 0, 0, 0);
          s[qf][cf] = __builtin_amdgcn_mfma_f32_16x16x32_bf16(kf1[cf], bq[qf][1], s0, 0, 0, 0);
        }
      __builtin_amdgcn_s_setprio(0);
      const char* curv = curs + 8192;
      bf16x8 vf0[4], vf1[4];
#pragma unroll
      for (int df = 0; df < 4; ++df) {
        vf0[df] = *(const bf16x8*)(curv + df * 2048 + koffA);
        vf1[df] = *(const bf16x8*)(curv + df * 2048 + koffB);
      }
#pragma unroll
      for (int qf = 0; qf < 2; ++qf) {
        f32x4 s0 = s[qf][0], s1 = s[qf][1], s2 = s[qf][2], s3 = s[qf][3];
        // P = exp2(S), no shift (ratio cancels exactly in O/l)
        u32x4 w0, w1;
        w0[0] = cvtpk_bf16(exp2_fast(s0[0]), exp2_fast(s0[1]));
        w0[1] = cvtpk_bf16(exp2_fast(s0[2]), exp2_fast(s0[3]));
        w0[2] = cvtpk_bf16(exp2_fast(s1[0]), exp2_fast(s1[1]));
        w0[3] = cvtpk_bf16(exp2_fast(s1[2]), exp2_fast(s1[3]));
        w1[0] = cvtpk_bf16(exp2_fast(s2[0]), exp2_fast(s2[1]));
        w1[1] = cvtpk_bf16(exp2_fast(s2[2]), exp2_fast(s2[3]));
        w1[2] = cvtpk_bf16(exp2_fast(s3[0]), exp2_fast(s3[1]));
        w1[3] = cvtpk_bf16(exp2_fast(s3[2]), exp2_fast(s3[3]));
        bf16x8 pb0 = __builtin_bit_cast(bf16x8, w0);
        bf16x8 pb1 = __builtin_bit_cast(bf16x8, w1);
        __builtin_amdgcn_s_setprio(1);
#pragma unroll
        for (int df = 0; df < 4; ++df) {
          oacc[df][qf] = __builtin_amdgcn_mfma_f32_16x16x32_bf16(vf0[df], pb0, oacc[df][qf], 0, 0, 0);
          oacc[df][qf] = __builtin_amdgcn_mfma_f32_16x16x32_bf16(vf1[df], pb1, oacc[df][qf], 0, 0, 0);
        }
        // l row-sum: ones-A MFMA sums P over all 32 k-slots (cross-lane complete)
        lacc[qf] = __builtin_amdgcn_mfma_f32_16x16x32_bf16(ones, pb0, lacc[qf], 0, 0, 0);
        lacc[qf] = __builtin_amdgcn_mfma_f32_16x16x32_bf16(ones, pb1, lacc[qf], 0, 0, 0);
        __builtin_amdgcn_s_setprio(0);
      }
    }
    drain_vm();
    __syncthreads();
  }
  // epilogue: transpose via wave-private swizzled patch in buffer-0 K0 region.
  // lacc[qf][0] is the COMPLETE l for column q (ones-MFMA summed across lanes).
  char* myT = lds + wave * 2048;
#pragma unroll
  for (int qf = 0; qf < 2; ++qf) {
    const float inv = 1.f / lacc[qf][0];
#pragma unroll
    for (int df = 0; df < 4; ++df)
#pragma unroll
      for (int h = 0; h < 2; ++h) {
        u32 w = cvtpk_bf16(oacc[df][qf][2 * h] * inv, oacc[df][qf][2 * h + 1] * inv);
        int X = (df * 16 + 4 * g + 2 * h) * 2;
        *(u32*)(myT + q * 128 + (X ^ ((q & 7) << 4))) = w;
      }
#pragma unroll
    for (int h = 0; h < 2; ++h) {
      int q2 = h * 8 + (lane >> 3);
      int c = lane & 7;
      bf16x8 vrow = *(const bf16x8*)(myT + q2 * 128 + ((c * 16) ^ ((q2 & 7) << 4)));
      int prow = qrowbase + qf * 16 + q2;
      *(bf16x8*)(aoT + (size_t)(b * NS + prow) * NC + n * 64 + c * 8) = vrow;
    }
  }
}

// ---------------- K4: out gemm_bt (counted-vmcnt 2-barrier pipeline) ---------
__global__ __launch_bounds__(256) void out_gemm(const u16* __restrict__ A,
                                                const u16* __restrict__ BT,
                                                const float* __restrict__ bias,
                                                const float* __restrict__ xres,
                                                float* __restrict__ out) {
  __shared__ char lds[32768];
  const int t = threadIdx.x, wave = t >> 6, lane = t & 63;
  int lin = blockIdx.x;
  int swz = (lin & 7) * 32 + (lin >> 3);
  const int bn = (swz & 7) * 128;
  const int bm = ((swz >> 3) & 3) * 128;
  const int bb = swz >> 5;
  const u16* Bt = BT + (size_t)bb * NS * NC;
  const int wm = wave >> 1, wn = wave & 1;
  f32x4 acc[4][4];
#pragma unroll
  for (int i = 0; i < 4; ++i)
#pragma unroll
    for (int j = 0; j < 4; ++j) acc[i][j] = (f32x4){0.f, 0.f, 0.f, 0.f};

  int c0 = t, c1 = 256 + t;
  int r0 = c0 >> 2, r1 = c1 >> 2;
  int h0 = (c0 & 3) ^ ((c0 >> 3) & 3), h1 = (c1 & 3) ^ ((c1 >> 3) & 3);
  const u16* a0 = A  + (size_t)(bm + r0) * NC + h0 * 8;
  const u16* a1 = A  + (size_t)(bm + r1) * NC + h1 * 8;
  const u16* b0 = Bt + (size_t)(bn + r0) * NC + h0 * 8;
  const u16* b1 = Bt + (size_t)(bn + r1) * NC + h1 * 8;

  gll16(lds + c0 * 16, a0); gll16(lds + c1 * 16, a1);
  gll16(lds + 8192 + c0 * 16, b0); gll16(lds + 8192 + c1 * 16, b1);
  drain_vm();
  __syncthreads();

  for (int ks = 0; ks < 16; ++ks) {
    const char* cur = lds + ((ks & 1) << 14);
    if (ks < 15) {
      char* nxt = lds + (((ks + 1) & 1) << 14);
      int ko = (ks + 1) * 32;
      gll16(nxt + c0 * 16,        a0 + ko);
      gll16(nxt + c1 * 16,        a1 + ko);
      gll16(nxt + 8192 + c0 * 16, b0 + ko);
      gll16(nxt + 8192 + c1 * 16, b1 + ko);
      wait_vm4();
    } else {
      drain_vm();
    }
    __builtin_amdgcn_s_barrier();
    __builtin_amdgcn_sched_barrier(0);
    bf16x8 af[4], bfr[4];
#pragma unroll
    for (int mf = 0; mf < 4; ++mf) {
      int row = wm * 64 + mf * 16 + (lane & 15);
      int cb = ((lane >> 4) * 16) ^ (((row >> 1) & 3) << 4);
      af[mf] = *(const bf16x8*)(cur + row * 64 + cb);
    }
#pragma unroll
    for (int nf = 0; nf < 4; ++nf) {
      int row = wn * 64 + nf * 16 + (lane & 15);
      int cb = ((lane >> 4) * 16) ^ (((row >> 1) & 3) << 4);
      bfr[nf] = *(const bf16x8*)(cur + 8192 + row * 64 + cb);
    }
#pragma unroll
    for (int mf = 0; mf < 4; ++mf)
#pragma unroll
      for (int nf = 0; nf < 4; ++nf)
        acc[mf][nf] = __builtin_amdgcn_mfma_f32_16x16x32_bf16(af[mf], bfr[nf], acc[mf][nf], 0, 0, 0);
    __builtin_amdgcn_s_barrier();
  }
#pragma unroll
  for (int mf = 0; mf < 4; ++mf) {
#pragma unroll
    for (int j = 0; j < 4; ++j) {
      int o = bm + wm * 64 + mf * 16 + (lane >> 4) * 4 + j;
      float bv = bias[o];
#pragma unroll
      for (int nf = 0; nf < 4; ++nf) {
        int p = bn + wn * 64 + nf * 16 + (lane & 15);
        size_t idx = (size_t)(bb * NC + o) * NS + p;
        out[idx] = acc[mf][nf][j] + bv + xres[idx];
      }
    }
  }
}

extern "C" void kernel_launch(void* const* d_in, const int* in_sizes, int n_in,
                              void* d_out, int out_size, void* d_ws, size_t ws_size,
                              hipStream_t stream) {
  const float* x     = (const float*)d_in[0];
  const float* gn_w  = (const float*)d_in[1];
  const float* gn_b  = (const float*)d_in[2];
  const float* qkv_w = (const float*)d_in[3];
  const float* qkv_b = (const float*)d_in[4];
  const float* out_w = (const float*)d_in[5];
  const float* out_b = (const float*)d_in[6];
  float* out = (float*)d_out;
  char* ws = (char*)d_ws;

  u16* wq  = (u16*)(ws);
  u16* wo  = (u16*)(ws + 1572864);
  u16* xnT = (u16*)(ws + 2097152);
  u16* kb  = (u16*)(ws + 10485760);
  u16* vb  = (u16*)(ws + 18874368);
  u16* aoT = (u16*)(ws + 2097152);   // overlaps xnT (sequentially dead)
  u16* qb  = (u16*)d_out;            // scratch use of d_out; overwritten by out_gemm

  gn_kernel<<<dim3(NB * NG), dim3(1024), 0, stream>>>(x, gn_w, gn_b, xnT, qkv_w, out_w, wq, wo);
  qkv_gemm<<<dim3(768), dim3(256), 0, stream>>>(wq, xnT, qkv_b, qb, kb, vb);
  attn_kernel<<<dim3(512), dim3(256), 0, stream>>>(qb, kb, vb, aoT);
  out_gemm<<<dim3(256), dim3(256), 0, stream>>>(wo, aoT, out_b, x, out);
}